// Round 1
// baseline (36.310 us; speedup 1.0000x reference)
//
#include <hip/hip_runtime.h>

// MIL loss: per-batch masked max over H*W, then mean BCE-with-logits over B.
// B=128, H=W=512, zones int32 in [0,50), cats int32 in [0,50), labels {0,1}.

constexpr int B   = 128;
constexpr int HW  = 512 * 512;          // 262144 pixels per batch
constexpr int TPB = 256;                // threads per block
constexpr int BPB = 32;                 // blocks per batch
constexpr int V4_PER_BATCH = HW / 4;    // 65536 int4/float4 per batch
constexpr int VEC_PER_THREAD = V4_PER_BATCH / (TPB * BPB);  // = 8
constexpr float NEG = -1e30f;

__global__ __launch_bounds__(TPB) void mil_stage1(
    const float* __restrict__ logits,
    const int*   __restrict__ zones,
    const int*   __restrict__ cats,
    float* __restrict__ pmax,
    int*   __restrict__ pany)
{
    const int b   = blockIdx.x / BPB;
    const int blk = blockIdx.x % BPB;
    const int cat = cats[b];            // uniform across block

    float m  = NEG;
    int   any = 0;

    if (cat > 0) {                      // cat<=0 => mask identically false
        const int4*   z4 = reinterpret_cast<const int4*>(zones)  + (size_t)b * V4_PER_BATCH;
        const float4* l4 = reinterpret_cast<const float4*>(logits) + (size_t)b * V4_PER_BATCH;
        const int base = blk * (TPB * VEC_PER_THREAD);
#pragma unroll
        for (int it = 0; it < VEC_PER_THREAD; ++it) {
            const int idx = base + it * TPB + threadIdx.x;
            const int4 z = z4[idx];
            // cat > 0 is uniform-true here, so (z==cat && z>0) == (z==cat)
            const bool c0 = (z.x == cat);
            const bool c1 = (z.y == cat);
            const bool c2 = (z.z == cat);
            const bool c3 = (z.w == cat);
            if (c0 | c1 | c2 | c3) {
                const float4 v = l4[idx];   // predicated: only lanes with a hit fetch
                if (c0) m = fmaxf(m, v.x);
                if (c1) m = fmaxf(m, v.y);
                if (c2) m = fmaxf(m, v.z);
                if (c3) m = fmaxf(m, v.w);
                any = 1;
            }
        }
    }

    // wave (64-lane) reduction
#pragma unroll
    for (int off = 32; off > 0; off >>= 1) {
        m   = fmaxf(m, __shfl_down(m, off, 64));
        any |= __shfl_down(any, off, 64);
    }

    __shared__ float sm[TPB / 64];
    __shared__ int   sa[TPB / 64];
    const int lane = threadIdx.x & 63;
    const int wid  = threadIdx.x >> 6;
    if (lane == 0) { sm[wid] = m; sa[wid] = any; }
    __syncthreads();
    if (threadIdx.x == 0) {
        float mm = sm[0];
        int   aa = sa[0];
#pragma unroll
        for (int w = 1; w < TPB / 64; ++w) { mm = fmaxf(mm, sm[w]); aa |= sa[w]; }
        pmax[b * BPB + blk] = mm;
        pany[b * BPB + blk] = aa;
    }
}

__global__ __launch_bounds__(128) void mil_stage2(
    const float* __restrict__ pmax,
    const int*   __restrict__ pany,
    const int*   __restrict__ labels,
    float* __restrict__ out)
{
    const int b = threadIdx.x;          // 0..127, one thread per batch
    float mm = NEG;
    int   aa = 0;
#pragma unroll
    for (int k = 0; k < BPB; ++k) {
        mm = fmaxf(mm, pmax[b * BPB + k]);
        aa |= pany[b * BPB + k];
    }
    const float s = aa ? mm : 0.0f;
    const float y = (float)labels[b];
    float loss = fmaxf(s, 0.0f) - s * y + log1pf(expf(-fabsf(s)));

    // sum-reduce 128 threads (2 waves)
#pragma unroll
    for (int off = 32; off > 0; off >>= 1)
        loss += __shfl_down(loss, off, 64);

    __shared__ float ss[2];
    const int lane = threadIdx.x & 63;
    const int wid  = threadIdx.x >> 6;
    if (lane == 0) ss[wid] = loss;
    __syncthreads();
    if (threadIdx.x == 0) out[0] = (ss[0] + ss[1]) / (float)B;
}

extern "C" void kernel_launch(void* const* d_in, const int* in_sizes, int n_in,
                              void* d_out, int out_size, void* d_ws, size_t ws_size,
                              hipStream_t stream)
{
    const float* logits = (const float*)d_in[0];   // (B,1,H,W) f32
    const int*   zones  = (const int*)  d_in[1];   // (B,H,W)  i32
    const int*   cats   = (const int*)  d_in[2];   // (B,)     i32
    const int*   labels = (const int*)  d_in[3];   // (B,)     i32
    float*       out    = (float*)d_out;

    float* pmax = (float*)d_ws;                              // B*BPB floats
    int*   pany = (int*)((char*)d_ws + B * BPB * sizeof(float));

    mil_stage1<<<B * BPB, TPB, 0, stream>>>(logits, zones, cats, pmax, pany);
    mil_stage2<<<1, 128, 0, stream>>>(pmax, pany, labels, out);
}

// Round 3
// 35.317 us; speedup vs baseline: 1.0281x; 1.0281x over previous
//
#include <hip/hip_runtime.h>

// MIL loss: per-batch masked max over H*W, then mean BCE-with-logits over B.
// B=128, H=W=512, zones int32 in [0,50), cats int32 in [0,50), labels {0,1}.
//
// Memory-bound: must stream all of zones (134 MB); logits fetched only where
// a 64B sector contains a zone==cat hit (~28-48% of lines at 1/50 density).

typedef int   i32x4 __attribute__((ext_vector_type(4)));   // true clang vectors:
typedef float f32x4 __attribute__((ext_vector_type(4)));   // nontemporal builtin needs these

constexpr int B   = 128;
constexpr int HW  = 512 * 512;          // 262144 pixels per batch
constexpr int TPB = 256;                // threads per block
constexpr int BPB = 16;                 // blocks per batch -> grid 2048 = 8 blocks/CU, one full round
constexpr int V4_PER_BATCH = HW / 4;    // 65536 vec4 per batch
constexpr int VPT = V4_PER_BATCH / (TPB * BPB);  // = 16 vec4 per thread
constexpr float NEG = -1e30f;

__global__ __launch_bounds__(TPB) void mil_stage1(
    const float* __restrict__ logits,
    const int*   __restrict__ zones,
    const int*   __restrict__ cats,
    float* __restrict__ pmax,
    int*   __restrict__ pany)
{
    const int b   = blockIdx.x / BPB;
    const int blk = blockIdx.x % BPB;
    const int cat = cats[b];            // uniform across block

    float m   = NEG;
    int   any = 0;

    if (cat > 0) {                      // cat<=0 => mask identically false for the batch
        const i32x4* z4 = reinterpret_cast<const i32x4*>(zones)
                        + (size_t)b * V4_PER_BATCH + (size_t)blk * (TPB * VPT);
        const f32x4* l4 = reinterpret_cast<const f32x4*>(logits)
                        + (size_t)b * V4_PER_BATCH + (size_t)blk * (TPB * VPT);

        // depth-2 manual pipeline on the zone stream: keep the NEXT vec4 load
        // in flight while testing/consuming the current one.
        i32x4 z = __builtin_nontemporal_load(&z4[threadIdx.x]);
#pragma unroll
        for (int it = 0; it < VPT; ++it) {
            i32x4 zn;
            if (it + 1 < VPT)
                zn = __builtin_nontemporal_load(&z4[threadIdx.x + (it + 1) * TPB]);

            // cat > 0 uniform-true here, so (z==cat && z>0) == (z==cat)
            const bool c0 = (z.x == cat);
            const bool c1 = (z.y == cat);
            const bool c2 = (z.z == cat);
            const bool c3 = (z.w == cat);
            if (c0 | c1 | c2 | c3) {
                const f32x4 v = __builtin_nontemporal_load(&l4[threadIdx.x + it * TPB]);
                if (c0) m = fmaxf(m, v.x);
                if (c1) m = fmaxf(m, v.y);
                if (c2) m = fmaxf(m, v.z);
                if (c3) m = fmaxf(m, v.w);
                any = 1;
            }
            z = zn;
        }
    }

    // wave (64-lane) down reduction
#pragma unroll
    for (int off = 32; off > 0; off >>= 1) {
        m   = fmaxf(m, __shfl_down(m, off, 64));
        any |= __shfl_down(any, off, 64);
    }

    __shared__ float sm[TPB / 64];
    __shared__ int   sa[TPB / 64];
    const int lane = threadIdx.x & 63;
    const int wid  = threadIdx.x >> 6;
    if (lane == 0) { sm[wid] = m; sa[wid] = any; }
    __syncthreads();
    if (threadIdx.x == 0) {
        float mm = sm[0];
        int   aa = sa[0];
#pragma unroll
        for (int w = 1; w < TPB / 64; ++w) { mm = fmaxf(mm, sm[w]); aa |= sa[w]; }
        pmax[b * BPB + blk] = mm;
        pany[b * BPB + blk] = aa;
    }
}

__global__ __launch_bounds__(128) void mil_stage2(
    const float* __restrict__ pmax,
    const int*   __restrict__ pany,
    const int*   __restrict__ labels,
    float* __restrict__ out)
{
    const int b = threadIdx.x;          // 0..127, one thread per batch
    float mm = NEG;
    int   aa = 0;
#pragma unroll
    for (int k = 0; k < BPB; ++k) {
        mm = fmaxf(mm, pmax[b * BPB + k]);
        aa |= pany[b * BPB + k];
    }
    const float s = aa ? mm : 0.0f;
    const float y = (float)labels[b];
    float loss = fmaxf(s, 0.0f) - s * y + log1pf(expf(-fabsf(s)));

    // sum-reduce 128 threads (2 waves)
#pragma unroll
    for (int off = 32; off > 0; off >>= 1)
        loss += __shfl_down(loss, off, 64);

    __shared__ float ss[2];
    const int lane = threadIdx.x & 63;
    const int wid  = threadIdx.x >> 6;
    if (lane == 0) ss[wid] = loss;
    __syncthreads();
    if (threadIdx.x == 0) out[0] = (ss[0] + ss[1]) / (float)B;
}

extern "C" void kernel_launch(void* const* d_in, const int* in_sizes, int n_in,
                              void* d_out, int out_size, void* d_ws, size_t ws_size,
                              hipStream_t stream)
{
    const float* logits = (const float*)d_in[0];   // (B,1,H,W) f32
    const int*   zones  = (const int*)  d_in[1];   // (B,H,W)  i32
    const int*   cats   = (const int*)  d_in[2];   // (B,)     i32
    const int*   labels = (const int*)  d_in[3];   // (B,)     i32
    float*       out    = (float*)d_out;

    float* pmax = (float*)d_ws;                              // B*BPB floats
    int*   pany = (int*)((char*)d_ws + B * BPB * sizeof(float));

    mil_stage1<<<B * BPB, TPB, 0, stream>>>(logits, zones, cats, pmax, pany);
    mil_stage2<<<1, 128, 0, stream>>>(pmax, pany, labels, out);
}